// Round 12
// baseline (214.013 us; speedup 1.0000x reference)
//
#include <hip/hip_runtime.h>

#define NN 51
#define DD 128
#define RS 132    // LDS row stride (words)
#define NT 64
#define NINFF (-__builtin_inff())

__device__ __forceinline__ float dot4(const float4 a, const float4 b) {
  return a.x * b.x + a.y * b.y + a.z * b.z + a.w * b.w;
}

// ---- DPP cross-lane (VALU pipe) ----
template<int CTRL>
__device__ __forceinline__ float dppf(float x, float idf) {
  return __int_as_float(__builtin_amdgcn_update_dpp(
      __float_as_int(idf), __float_as_int(x), CTRL, 0xf, 0xf, false));
}
__device__ __forceinline__ float readlanef(float x, int lane) {
  return __int_as_float(__builtin_amdgcn_readlane(__float_as_int(x), lane));
}
__device__ __forceinline__ float bcast63(float x) { return readlanef(x, 63); }
__device__ __forceinline__ float wave_max_b(float x) {
  x = fmaxf(x, dppf<0x111>(x, NINFF));
  x = fmaxf(x, dppf<0x112>(x, NINFF));
  x = fmaxf(x, dppf<0x114>(x, NINFF));
  x = fmaxf(x, dppf<0x118>(x, NINFF));
  x = fmaxf(x, dppf<0x142>(x, NINFF));
  x = fmaxf(x, dppf<0x143>(x, NINFF));
  return bcast63(x);
}
__device__ __forceinline__ float wave_sum_b(float x) {
  x += dppf<0x111>(x, 0.f);
  x += dppf<0x112>(x, 0.f);
  x += dppf<0x114>(x, 0.f);
  x += dppf<0x118>(x, 0.f);
  x += dppf<0x142>(x, 0.f);
  x += dppf<0x143>(x, 0.f);
  return bcast63(x);
}
__device__ __forceinline__ float row16_sum(float x) {  // totals at lanes 15/31/47/63
  x += dppf<0x111>(x, 0.f);
  x += dppf<0x112>(x, 0.f);
  x += dppf<0x114>(x, 0.f);
  x += dppf<0x118>(x, 0.f);
  return x;
}
__device__ __forceinline__ float grp8_sum(float x) {   // total in ALL lanes of 8-group
  x += dppf<0xB1>(x, 0.f);   // quad_perm xor1
  x += dppf<0x4E>(x, 0.f);   // quad_perm xor2
  x += dppf<0x141>(x, 0.f);  // ROW_HALF_MIRROR: partner quad total
  return x;
}

// JAX threefry2x32 (20 rounds), exact.
__device__ __forceinline__ void tf2x32(unsigned k0, unsigned k1, unsigned &x0, unsigned &x1) {
  const unsigned ks2 = k0 ^ k1 ^ 0x1BD11BDAu;
  const unsigned ka[5] = {k1, ks2, k0, k1, ks2};
  const unsigned kb[5] = {ks2 + 1u, k0 + 2u, k1 + 3u, ks2 + 4u, k0 + 5u};
  x0 += k0; x1 += k1;
#pragma unroll
  for (int g = 0; g < 5; ++g) {
    const int r0 = (g & 1) ? 17 : 13;
    const int r1 = (g & 1) ? 29 : 15;
    const int r2 = (g & 1) ? 16 : 26;
    const int r3 = (g & 1) ? 24 : 6;
    x0 += x1; x1 = (x1 << r0) | (x1 >> (32 - r0)); x1 ^= x0;
    x0 += x1; x1 = (x1 << r1) | (x1 >> (32 - r1)); x1 ^= x0;
    x0 += x1; x1 = (x1 << r2) | (x1 >> (32 - r2)); x1 ^= x0;
    x0 += x1; x1 = (x1 << r3) | (x1 >> (32 - r3)); x1 ^= x0;
    x0 += ka[g]; x1 += kb[g];
  }
}

__device__ __forceinline__ float gumbel_from(unsigned k0, unsigned k1, unsigned ctr) {
  unsigned x0 = 0u, x1 = ctr;
  tf2x32(k0, k1, x0, x1);
  const unsigned bits = x0 ^ x1;
  const float fl = __uint_as_float((bits >> 9) | 0x3f800000u) - 1.0f;
  const float TINY = 1.17549435e-38f;
  const float uu = fmaxf(TINY, fl + TINY);
  return -logf(-logf(uu));
}

__global__ __launch_bounds__(1024, 1) void decode_kernel(
    const float* __restrict__ enc, const float* __restrict__ pool_in,
    const float* __restrict__ cap_p, const float* __restrict__ demand,
    const float* __restrict__ fc_w, const float* __restrict__ fc1,
    const float* __restrict__ wq, const float* __restrict__ wk,
    const float* __restrict__ wv, const float* __restrict__ wo,
    const float* __restrict__ wkp, const float* __restrict__ T_p,
    const int* __restrict__ ns_p, const int* __restrict__ greedy_p,
    float* __restrict__ out) {
  __shared__ __align__(16) float Ksh[NN * RS];
  __shared__ __align__(16) float Vsh[52 * RS];     // row 51 zero
  __shared__ __align__(16) float KP2sh[NN * RS];
  __shared__ __align__(16) float EQsh[NN * RS];
  __shared__ __align__(16) float qpoolL[NT * DD];  // staged enc -> pools -> qpool[t]
  __shared__ __align__(16) float pcb2[2][8 * 64];  // comp partials, double-buffered
  __shared__ __align__(16) float poolB[2][DD];
  __shared__ __align__(16) float wrowL[DD];
  __shared__ __align__(16) float gumT[NT * NN];    // precomputed gumbel table
  __shared__ float demL[NN];
  __shared__ float actsL[NT];
  __shared__ unsigned keysL[2 * NT];

  const int b = blockIdx.x, tid = threadIdx.x;
  const int Bn = gridDim.x;
  const int w = tid >> 6, l = tid & 63;
  int ns = *ns_p; if (ns > NT) ns = NT;
  const int greedy = *greedy_p;
  const float Tval = *T_p;
  const float cap0 = *cap_p;

  // ---- stage ----
  {
    const float4* src = (const float4*)(enc + (size_t)b * NN * DD);
    float4* dst = (float4*)qpoolL;
    for (int e = tid; e < NN * DD / 4; e += 1024) dst[e] = src[e];
  }
  if (tid < 128) poolB[0][tid] = pool_in[b * DD + tid];
  if (tid < RS)  Vsh[51 * RS + tid] = 0.f;
  if (tid < NN)  demL[tid] = demand[b * NN + tid];
  if (tid < ns) {  // fold_in(key(1234),0), then partitionable split child t
    unsigned a0 = 0u, a1 = 0u;
    tf2x32(0u, 1234u, a0, a1);
    unsigned x0 = 0u, x1 = (unsigned)tid;
    tf2x32(a0, a1, x0, x1);
    keysL[2 * tid] = x0; keysL[2 * tid + 1] = x1;
  }
  __syncthreads();  // S1

  float dem_l = (l < NN) ? demL[l] : 0.f;

  // gumbel table for all steps
  if (!greedy) {
    for (int job = tid; job < ns * NN; job += 1024) {
      const int t = job / NN, n = job - t * NN;
      gumT[job] = gumbel_from(keysL[2 * t], keysL[2 * t + 1], (unsigned)(b * NN + n));
    }
  }
  // wrow[c] = fc_w[128,:] @ wq[:,c] via 8-lane DPP groups (no scratch buffer)
  {
    const int c = tid >> 3, qrt = tid & 7;
    const float* fr = fc_w + 128 * DD;
    float s = 0.f;
#pragma unroll
    for (int i = 0; i < 16; ++i) {
      const int j = qrt * 16 + i;
      s += fr[j] * wq[j * DD + c];
    }
    s = grp8_sum(s);
    if (qrt == 0) wrowL[c] = s;
  }

  const int g8 = tid >> 7, cc = tid & 127;
  const int n0 = g8 * 7;
  const int cnt7 = (n0 + 7 <= NN) ? 7 : (NN - n0);   // g8=7 -> 2 rows

  // ---- phase A (fused): K, V, T1, T2 in one E pass (7 rows/group) ----
  {
    float aK[7], aV[7], aT1[7], aT2[7];
#pragma unroll
    for (int r = 0; r < 7; ++r) { aK[r] = 0.f; aV[r] = 0.f; aT1[r] = 0.f; aT2[r] = 0.f; }
    for (int i = 0; i < DD; i += 4) {
      const float k0 = wk[(i + 0) * DD + cc], k1 = wk[(i + 1) * DD + cc];
      const float k2 = wk[(i + 2) * DD + cc], k3 = wk[(i + 3) * DD + cc];
      const float v0 = wv[(i + 0) * DD + cc], v1 = wv[(i + 1) * DD + cc];
      const float v2 = wv[(i + 2) * DD + cc], v3 = wv[(i + 3) * DD + cc];
      const float f0 = fc_w[(i + 0) * DD + cc], f1 = fc_w[(i + 1) * DD + cc];
      const float f2 = fc_w[(i + 2) * DD + cc], f3 = fc_w[(i + 3) * DD + cc];
      const float p0 = wkp[(i + 0) * DD + cc], p1 = wkp[(i + 1) * DD + cc];
      const float p2 = wkp[(i + 2) * DD + cc], p3 = wkp[(i + 3) * DD + cc];
#pragma unroll
      for (int r = 0; r < 7; ++r) {
        if (r < cnt7) {
          const float4 e4 = *(const float4*)&qpoolL[(n0 + r) * DD + i];
          aK[r]  += e4.x * k0 + e4.y * k1 + e4.z * k2 + e4.w * k3;
          aV[r]  += e4.x * v0 + e4.y * v1 + e4.z * v2 + e4.w * v3;
          aT1[r] += e4.x * f0 + e4.y * f1 + e4.z * f2 + e4.w * f3;
          aT2[r] += e4.x * p0 + e4.y * p1 + e4.z * p2 + e4.w * p3;
        }
      }
    }
#pragma unroll
    for (int r = 0; r < 7; ++r) {
      if (r < cnt7) {
        Ksh[(n0 + r) * RS + cc]   = aK[r];
        Vsh[(n0 + r) * RS + cc]   = aV[r];
        EQsh[(n0 + r) * RS + cc]  = aT1[r];
        KP2sh[(n0 + r) * RS + cc] = aT2[r];
      }
    }
  }
  __syncthreads();  // S3

  // ---- phase B (fused, in place): EQ = T1@wq ; KP2 = T2@wo^T ----
  {
    float aEQ[7], aKP[7];
#pragma unroll
    for (int r = 0; r < 7; ++r) { aEQ[r] = 0.f; aKP[r] = 0.f; }
    for (int i = 0; i < DD; i += 4) {
      const float q0 = wq[(i + 0) * DD + cc], q1 = wq[(i + 1) * DD + cc];
      const float q2 = wq[(i + 2) * DD + cc], q3 = wq[(i + 3) * DD + cc];
      const float4 w4 = *(const float4*)&wo[cc * DD + i];
#pragma unroll
      for (int r = 0; r < 7; ++r) {
        if (r < cnt7) {
          const float4 t1 = *(const float4*)&EQsh[(n0 + r) * RS + i];
          const float4 t2 = *(const float4*)&KP2sh[(n0 + r) * RS + i];
          aEQ[r] += t1.x * q0 + t1.y * q1 + t1.z * q2 + t1.w * q3;
          aKP[r] += dot4(t2, w4);
        }
      }
    }
    __syncthreads();  // S4
#pragma unroll
    for (int r = 0; r < 7; ++r) {
      if (r < cnt7) {
        EQsh[(n0 + r) * RS + cc]  = aEQ[r];
        KP2sh[(n0 + r) * RS + cc] = aKP[r];
      }
    }
  }
  __syncthreads();  // S5

  // ---- preload static per-(wave,lane) register slices (heads = waves 0..7) ----
  float4 Kr0{0,0,0,0}, Kr1{0,0,0,0}, Kr2{0,0,0,0}, Kr3{0,0,0,0};
  float4 Pr0{0,0,0,0}, Pr1{0,0,0,0}, Pr2{0,0,0,0}, Pr3{0,0,0,0};
  float4 Vr0{0,0,0,0}, Vr1{0,0,0,0}, Vr2{0,0,0,0}, Vr3{0,0,0,0};
  float4 Wr0{0,0,0,0}, Wr1{0,0,0,0}, Wr2{0,0,0,0}, Wr3{0,0,0,0};
  const int nn0 = l & 15, dq = l >> 4;
  if (w < 8) {
    const int rowc = (l < NN) ? l : 0;
    const float4* kbase = (const float4*)&Ksh[rowc * RS + w * 16];
    Kr0 = kbase[0]; Kr1 = kbase[1]; Kr2 = kbase[2]; Kr3 = kbase[3];
    const float4* pbase = (const float4*)&KP2sh[rowc * RS + w * 16];
    Pr0 = pbase[0]; Pr1 = pbase[1]; Pr2 = pbase[2]; Pr3 = pbase[3];
    const int vr3 = (nn0 + 48 <= 51) ? (nn0 + 48) : 51;
    Vr0 = *(const float4*)&Vsh[(nn0 +  0) * RS + w * 16 + dq * 4];
    Vr1 = *(const float4*)&Vsh[(nn0 + 16) * RS + w * 16 + dq * 4];
    Vr2 = *(const float4*)&Vsh[(nn0 + 32) * RS + w * 16 + dq * 4];
    Vr3 = *(const float4*)&Vsh[vr3 * RS + w * 16 + dq * 4];
    const float4* wbase = (const float4*)&wrowL[w * 16];
    Wr0 = wbase[0]; Wr1 = wbase[1]; Wr2 = wbase[2]; Wr3 = wbase[3];
  }

  // ---- phase C: pool chain (1 barrier/t), then parallel @wq in place ----
  {
    const int colC = tid >> 3, qrt = tid & 7;
    float wfr[16];
#pragma unroll
    for (int i = 0; i < 16; ++i) wfr[i] = fc1[(qrt * 16 + i) * DD + colC];
    int cur = 0;
    for (int t = 0; t < ns; ++t) {
      float s = 0.f;
#pragma unroll
      for (int i = 0; i < 16; ++i) s += poolB[cur][qrt * 16 + i] * wfr[i];
      s = grp8_sum(s);
      if (qrt == 0) {
        qpoolL[t * DD + colC] = s;      // pool_{t+1}
        poolB[cur ^ 1][colC] = s;
      }
      cur ^= 1;
      __syncthreads();
    }
    const int qch = (ns + 7) >> 3;      // <= 8
    const int r0q = g8 * qch;
    int rcnt = ns - r0q; if (rcnt > qch) rcnt = qch; if (rcnt < 0) rcnt = 0;
    float acc[8];
#pragma unroll
    for (int r = 0; r < 8; ++r) acc[r] = 0.f;
    for (int i = 0; i < DD; i += 4) {
      const float q0 = wq[(i + 0) * DD + cc], q1 = wq[(i + 1) * DD + cc];
      const float q2 = wq[(i + 2) * DD + cc], q3 = wq[(i + 3) * DD + cc];
#pragma unroll
      for (int r = 0; r < 8; ++r) {
        if (r < rcnt) {
          const float4 p4 = *(const float4*)&qpoolL[(r0q + r) * DD + i];
          acc[r] += p4.x * q0 + p4.y * q1 + p4.z * q2 + p4.w * q3;
        }
      }
    }
    __syncthreads();
#pragma unroll
    for (int r = 0; r < 8; ++r)
      if (r < rcnt) qpoolL[(r0q + r) * DD + cc] = acc[r];
  }
  __syncthreads();

  // ---- preloop: replicated register state + qv for t=0 ----
  int m1 = (l == 0) ? 1 : 0;
  float dynr = cap0, depotr = 1.f, lpacc0 = 0.f, lpacc1 = 0.f;
  float4 qv0, qv1, qv2, qv3;
  if (w < 8) {
    const float4* eq = (const float4*)&EQsh[0 * RS + w * 16];
    const float4* qp = (const float4*)&qpoolL[0 * DD + w * 16];
    qv0.x = eq[0].x + cap0 * Wr0.x + qp[0].x; qv0.y = eq[0].y + cap0 * Wr0.y + qp[0].y;
    qv0.z = eq[0].z + cap0 * Wr0.z + qp[0].z; qv0.w = eq[0].w + cap0 * Wr0.w + qp[0].w;
    qv1.x = eq[1].x + cap0 * Wr1.x + qp[1].x; qv1.y = eq[1].y + cap0 * Wr1.y + qp[1].y;
    qv1.z = eq[1].z + cap0 * Wr1.z + qp[1].z; qv1.w = eq[1].w + cap0 * Wr1.w + qp[1].w;
    qv2.x = eq[2].x + cap0 * Wr2.x + qp[2].x; qv2.y = eq[2].y + cap0 * Wr2.y + qp[2].y;
    qv2.z = eq[2].z + cap0 * Wr2.z + qp[2].z; qv2.w = eq[2].w + cap0 * Wr2.w + qp[2].w;
    qv3.x = eq[3].x + cap0 * Wr3.x + qp[3].x; qv3.y = eq[3].y + cap0 * Wr3.y + qp[3].y;
    qv3.z = eq[3].z + cap0 * Wr3.z + qp[3].z; qv3.w = eq[3].w + cap0 * Wr3.w + qp[3].w;
  }

  // ---- decode: ONE barrier/step ----
  for (int t = 0; t < ns; ++t) {
    // X: waves 0-7 = heads; waves 8-15 idle
    if (w < 8) {
      const bool maskedl =
          (l == 0) ? (depotr > 0.f)
          : (l < NN ? ((m1 != 0) || (dem_l > dynr)) : true);
      float u1 = NINFF;
      if (l < NN && !maskedl)
        u1 = 0.25f * ((dot4(Kr0, qv0) + dot4(Kr1, qv1)) +
                      (dot4(Kr2, qv2) + dot4(Kr3, qv3)));
      const float mx = wave_max_b(u1);
      const float e = (u1 > NINFF) ? expf(u1 - mx) : 0.f;
      const float a0 = __shfl(e, nn0);
      const float a1 = __shfl(e, nn0 + 16);
      const float a2 = __shfl(e, nn0 + 32);
      const float a3 = __shfl(e, nn0 + 48);
      const float S = wave_sum_b(e);
      const float rS = 1.f / S;
      float ax = a0 * Vr0.x + a1 * Vr1.x + a2 * Vr2.x + a3 * Vr3.x;
      float ay = a0 * Vr0.y + a1 * Vr1.y + a2 * Vr2.y + a3 * Vr3.y;
      float az = a0 * Vr0.z + a1 * Vr1.z + a2 * Vr2.z + a3 * Vr3.z;
      float aw = a0 * Vr0.w + a1 * Vr1.w + a2 * Vr2.w + a3 * Vr3.w;
      ax = row16_sum(ax) * rS; ay = row16_sum(ay) * rS;
      az = row16_sum(az) * rS; aw = row16_sum(aw) * rS;
      const float g0  = readlanef(ax, 15), g1  = readlanef(ay, 15);
      const float g2  = readlanef(az, 15), g3  = readlanef(aw, 15);
      const float g4g = readlanef(ax, 31), g5  = readlanef(ay, 31);
      const float g6  = readlanef(az, 31), g7  = readlanef(aw, 31);
      const float g8r = readlanef(ax, 47), g9  = readlanef(ay, 47);
      const float g10 = readlanef(az, 47), g11 = readlanef(aw, 47);
      const float g12 = readlanef(ax, 63), g13 = readlanef(ay, 63);
      const float g14 = readlanef(az, 63), g15 = readlanef(aw, 63);
      const float part =
          ((Pr0.x * g0  + Pr0.y * g1  + Pr0.z * g2  + Pr0.w * g3) +
           (Pr1.x * g4g + Pr1.y * g5  + Pr1.z * g6  + Pr1.w * g7)) +
          ((Pr2.x * g8r + Pr2.y * g9  + Pr2.z * g10 + Pr2.w * g11) +
           (Pr3.x * g12 + Pr3.y * g13 + Pr3.z * g14 + Pr3.w * g15));
      pcb2[t & 1][w * 64 + l] = part;
    }
    __syncthreads();   // the ONLY barrier per step
    // Z: waves 0-8 replicate sampling/state; wave 8 also does LSE bookkeeping
    if (w <= 8) {
      const float pg = (!greedy && l < NN) ? gumT[t * NN + l] : 0.f;
      const float* pcb = pcb2[t & 1];
      float lgv = NINFF;
      {
        const float p0 = pcb[0 * 64 + l], p1 = pcb[1 * 64 + l];
        const float p2 = pcb[2 * 64 + l], p3 = pcb[3 * 64 + l];
        const float p4 = pcb[4 * 64 + l], p5 = pcb[5 * 64 + l];
        const float p6 = pcb[6 * 64 + l], p7 = pcb[7 * 64 + l];
        const float comp = (((p0 + p1) + (p2 + p3)) + ((p4 + p5) + (p6 + p7))) *
                           0.08838834764831845f;  // 128^-0.5
        const float lg = (10.f * tanhf(comp)) / Tval;
        const bool maskedn =
            (l == 0) ? (depotr > 0.f) : ((m1 != 0) || (dem_l > dynr));
        if (l < NN) lgv = maskedn ? NINFF : lg;
      }
      const float pv = (l < NN) ? (lgv + pg) : NINFF;
      const float vmax = wave_max_b(pv);
      const unsigned long long Meq = __ballot(pv == vmax);
      const int best = __ffsll(Meq) - 1;   // first max = jnp.argmax tie-break
      if (l == best) m1 = 1;
      const unsigned long long M = __ballot(m1 != 0);
      const int cntv = (int)__popcll(M & ~1ull);
      const float dem_b = readlanef(dem_l, best);
      dynr = (best == 0) ? cap0 : (dynr - dem_b);
      depotr = (best == 0) ? 1.f : 0.f;
      if (cntv >= NN - 1) depotr = 0.f;
      if (w == 8) {          // logp bookkeeping on an X-idle wave
        lpacc0 += readlanef(lgv, best);
        const float mm = wave_max_b(lgv);
        const float ee = wave_sum_b((lgv > NINFF) ? expf(lgv - mm) : 0.f);
        lpacc1 += mm + logf(ee);
      } else {
        if (w == 0 && l == 0) actsL[t] = (float)best;
        // next q slice (wave-uniform values)
        const int qidx = (t + 1 < ns) ? (t + 1) : 0;
        const float4* qp = (const float4*)&qpoolL[qidx * DD + w * 16];
        const float4 qp0 = qp[0], qp1 = qp[1], qp2 = qp[2], qp3 = qp[3];
        const float4* eq = (const float4*)&EQsh[best * RS + w * 16];
        qv0.x = eq[0].x + dynr * Wr0.x + qp0.x; qv0.y = eq[0].y + dynr * Wr0.y + qp0.y;
        qv0.z = eq[0].z + dynr * Wr0.z + qp0.z; qv0.w = eq[0].w + dynr * Wr0.w + qp0.w;
        qv1.x = eq[1].x + dynr * Wr1.x + qp1.x; qv1.y = eq[1].y + dynr * Wr1.y + qp1.y;
        qv1.z = eq[1].z + dynr * Wr1.z + qp1.z; qv1.w = eq[1].w + dynr * Wr1.w + qp1.w;
        qv2.x = eq[2].x + dynr * Wr2.x + qp2.x; qv2.y = eq[2].y + dynr * Wr2.y + qp2.y;
        qv2.z = eq[2].z + dynr * Wr2.z + qp2.z; qv2.w = eq[2].w + dynr * Wr2.w + qp2.w;
        qv3.x = eq[3].x + dynr * Wr3.x + qp3.x; qv3.y = eq[3].y + dynr * Wr3.y + qp3.y;
        qv3.z = eq[3].z + dynr * Wr3.z + qp3.z; qv3.w = eq[3].w + dynr * Wr3.w + qp3.w;
      }
    }
    // no barrier: pcb double-buffered; gumT read-only; actsL single-writer
  }
  __syncthreads();
  if (w == 0 && l < ns) out[b * ns + l] = actsL[l];
  if (w == 8 && l == 0) out[Bn * ns + b] = lpacc0 - lpacc1;
}

extern "C" void kernel_launch(void* const* d_in, const int* in_sizes, int n_in,
                              void* d_out, int out_size, void* d_ws, size_t ws_size,
                              hipStream_t stream) {
  const float* enc    = (const float*)d_in[0];
  const float* pool   = (const float*)d_in[1];
  const float* cap    = (const float*)d_in[2];
  const float* dem    = (const float*)d_in[3];
  const float* fc_w   = (const float*)d_in[4];
  const float* fc1_w  = (const float*)d_in[5];
  const float* wq     = (const float*)d_in[6];
  const float* wk     = (const float*)d_in[7];
  const float* wv     = (const float*)d_in[8];
  const float* wo     = (const float*)d_in[9];
  const float* wkp    = (const float*)d_in[10];
  const float* Tp     = (const float*)d_in[11];
  const int*   nsp    = (const int*)d_in[12];
  const int*   greedy = (const int*)d_in[14];
  float* out = (float*)d_out;

  const int B = in_sizes[1] / DD;  // pool is (B,128)

  hipLaunchKernelGGL(decode_kernel, dim3(B), dim3(1024), 0, stream,
                     enc, pool, cap, dem, fc_w, fc1_w, wq, wk, wv, wo, wkp,
                     Tp, nsp, greedy, out);
}

// Round 13
// 197.623 us; speedup vs baseline: 1.0829x; 1.0829x over previous
//
#include <hip/hip_runtime.h>

#define NN 51
#define DD 128
#define RS 132    // LDS row stride (words)
#define NT 64
#define NINFF (-__builtin_inff())

__device__ __forceinline__ float dot4(const float4 a, const float4 b) {
  return a.x * b.x + a.y * b.y + a.z * b.z + a.w * b.w;
}

// ---- DPP cross-lane (VALU pipe) ----
template<int CTRL>
__device__ __forceinline__ float dppf(float x, float idf) {
  return __int_as_float(__builtin_amdgcn_update_dpp(
      __float_as_int(idf), __float_as_int(x), CTRL, 0xf, 0xf, false));
}
__device__ __forceinline__ float readlanef(float x, int lane) {
  return __int_as_float(__builtin_amdgcn_readlane(__float_as_int(x), lane));
}
__device__ __forceinline__ float bcast63(float x) { return readlanef(x, 63); }
__device__ __forceinline__ float wave_max_b(float x) {
  x = fmaxf(x, dppf<0x111>(x, NINFF));
  x = fmaxf(x, dppf<0x112>(x, NINFF));
  x = fmaxf(x, dppf<0x114>(x, NINFF));
  x = fmaxf(x, dppf<0x118>(x, NINFF));
  x = fmaxf(x, dppf<0x142>(x, NINFF));
  x = fmaxf(x, dppf<0x143>(x, NINFF));
  return bcast63(x);
}
__device__ __forceinline__ float wave_sum_b(float x) {
  x += dppf<0x111>(x, 0.f);
  x += dppf<0x112>(x, 0.f);
  x += dppf<0x114>(x, 0.f);
  x += dppf<0x118>(x, 0.f);
  x += dppf<0x142>(x, 0.f);
  x += dppf<0x143>(x, 0.f);
  return bcast63(x);
}
__device__ __forceinline__ float row16_sum(float x) {  // totals at lanes 15/31/47/63
  x += dppf<0x111>(x, 0.f);
  x += dppf<0x112>(x, 0.f);
  x += dppf<0x114>(x, 0.f);
  x += dppf<0x118>(x, 0.f);
  return x;
}
__device__ __forceinline__ float quad_sum(float x) {   // total in all 4 lanes of quad
  x += dppf<0xB1>(x, 0.f);   // quad_perm [1,0,3,2]
  x += dppf<0x4E>(x, 0.f);   // quad_perm [2,3,0,1]
  return x;
}

// JAX threefry2x32 (20 rounds), exact.
__device__ __forceinline__ void tf2x32(unsigned k0, unsigned k1, unsigned &x0, unsigned &x1) {
  const unsigned ks2 = k0 ^ k1 ^ 0x1BD11BDAu;
  const unsigned ka[5] = {k1, ks2, k0, k1, ks2};
  const unsigned kb[5] = {ks2 + 1u, k0 + 2u, k1 + 3u, ks2 + 4u, k0 + 5u};
  x0 += k0; x1 += k1;
#pragma unroll
  for (int g = 0; g < 5; ++g) {
    const int r0 = (g & 1) ? 17 : 13;
    const int r1 = (g & 1) ? 29 : 15;
    const int r2 = (g & 1) ? 16 : 26;
    const int r3 = (g & 1) ? 24 : 6;
    x0 += x1; x1 = (x1 << r0) | (x1 >> (32 - r0)); x1 ^= x0;
    x0 += x1; x1 = (x1 << r1) | (x1 >> (32 - r1)); x1 ^= x0;
    x0 += x1; x1 = (x1 << r2) | (x1 >> (32 - r2)); x1 ^= x0;
    x0 += x1; x1 = (x1 << r3) | (x1 >> (32 - r3)); x1 ^= x0;
    x0 += ka[g]; x1 += kb[g];
  }
}

__device__ __forceinline__ float gumbel_from(unsigned k0, unsigned k1, unsigned ctr) {
  unsigned x0 = 0u, x1 = ctr;
  tf2x32(k0, k1, x0, x1);
  const unsigned bits = x0 ^ x1;
  const float fl = __uint_as_float((bits >> 9) | 0x3f800000u) - 1.0f;
  const float TINY = 1.17549435e-38f;
  const float uu = fmaxf(TINY, fl + TINY);
  return -logf(-logf(uu));
}

__global__ __launch_bounds__(512, 1) void decode_kernel(
    const float* __restrict__ enc, const float* __restrict__ pool_in,
    const float* __restrict__ cap_p, const float* __restrict__ demand,
    const float* __restrict__ fc_w, const float* __restrict__ fc1,
    const float* __restrict__ wq, const float* __restrict__ wk,
    const float* __restrict__ wv, const float* __restrict__ wo,
    const float* __restrict__ wkp, const float* __restrict__ T_p,
    const int* __restrict__ ns_p, const int* __restrict__ greedy_p,
    float* __restrict__ out) {
  __shared__ __align__(16) float Ksh[NN * RS];
  __shared__ __align__(16) float Vsh[52 * RS];     // row 51 zero
  __shared__ __align__(16) float KP2sh[NN * RS];
  __shared__ __align__(16) float EQsh[NN * RS];
  __shared__ __align__(16) float qpoolL[NT * DD];  // enc -> pools -> qpool[t] -> logits stash
  __shared__ __align__(16) float pcb2[2][8 * 64];  // comp partials (aliases partF early)
  __shared__ __align__(16) float poolB[2][DD];     // pool chain double buffer
  __shared__ __align__(16) float wrowL[DD];
  __shared__ __align__(16) float gumT[NT * NN];    // precomputed gumbel table
  __shared__ float demL[NN];
  __shared__ float actsL[NT];
  __shared__ float lseP[8];
  __shared__ unsigned keysL[2 * NT];

  const int b = blockIdx.x, tid = threadIdx.x;
  const int Bn = gridDim.x;
  const int w = tid >> 6, l = tid & 63;
  int ns = *ns_p; if (ns > NT) ns = NT;
  const int greedy = *greedy_p;
  const float Tval = *T_p;
  const float cap0 = *cap_p;
  float* partF = &pcb2[0][0];   // 512-float alias, preamble only

  // ---- stage ----
  {
    const float4* src = (const float4*)(enc + (size_t)b * NN * DD);
    float4* dst = (float4*)qpoolL;
    for (int e = tid; e < NN * DD / 4; e += 512) dst[e] = src[e];
  }
  if (tid < 128) poolB[0][tid] = pool_in[b * DD + tid];
  if (tid < RS)  Vsh[51 * RS + tid] = 0.f;
  if (tid < NN)  demL[tid] = demand[b * NN + tid];
  if (tid < ns) {  // fold_in(key(1234),0), then partitionable split child t
    unsigned a0 = 0u, a1 = 0u;
    tf2x32(0u, 1234u, a0, a1);
    unsigned x0 = 0u, x1 = (unsigned)tid;
    tf2x32(a0, a1, x0, x1);
    keysL[2 * tid] = x0; keysL[2 * tid + 1] = x1;
  }
  __syncthreads();  // S1

  float dem_l = (l < NN) ? demL[l] : 0.f;

  // gumbel table for all steps
  if (!greedy) {
    for (int job = tid; job < ns * NN; job += 512) {
      const int t = job / NN, n = job - t * NN;
      gumT[job] = gumbel_from(keysL[2 * t], keysL[2 * t + 1], (unsigned)(b * NN + n));
    }
  }
  // wrow partials
  {
    const int c = tid & 127, qd = tid >> 7;
    const float* fr = fc_w + 128 * DD;
    float s = 0.f;
    for (int j = qd * 32; j < qd * 32 + 32; ++j) s += fr[j] * wq[j * DD + c];
    partF[tid] = s;
  }
  __syncthreads();  // S2
  if (tid < 128)
    wrowL[tid] = partF[tid] + partF[tid + 128] + partF[tid + 256] + partF[tid + 384];

  const int g4 = tid >> 7, cc = tid & 127;
  const int n0 = g4 * 13, cnt13 = (g4 == 3) ? 12 : 13;

  // ---- phase A (fused): K, V, T1, T2 in one E pass ----
  {
    float aK[13], aV[13], aT1[13], aT2[13];
#pragma unroll
    for (int r = 0; r < 13; ++r) { aK[r] = 0.f; aV[r] = 0.f; aT1[r] = 0.f; aT2[r] = 0.f; }
    for (int i = 0; i < DD; i += 4) {
      const float k0 = wk[(i + 0) * DD + cc], k1 = wk[(i + 1) * DD + cc];
      const float k2 = wk[(i + 2) * DD + cc], k3 = wk[(i + 3) * DD + cc];
      const float v0 = wv[(i + 0) * DD + cc], v1 = wv[(i + 1) * DD + cc];
      const float v2 = wv[(i + 2) * DD + cc], v3 = wv[(i + 3) * DD + cc];
      const float f0 = fc_w[(i + 0) * DD + cc], f1 = fc_w[(i + 1) * DD + cc];
      const float f2 = fc_w[(i + 2) * DD + cc], f3 = fc_w[(i + 3) * DD + cc];
      const float p0 = wkp[(i + 0) * DD + cc], p1 = wkp[(i + 1) * DD + cc];
      const float p2 = wkp[(i + 2) * DD + cc], p3 = wkp[(i + 3) * DD + cc];
#pragma unroll
      for (int r = 0; r < 13; ++r) {
        if (r < cnt13) {
          const float4 e4 = *(const float4*)&qpoolL[(n0 + r) * DD + i];
          aK[r]  += e4.x * k0 + e4.y * k1 + e4.z * k2 + e4.w * k3;
          aV[r]  += e4.x * v0 + e4.y * v1 + e4.z * v2 + e4.w * v3;
          aT1[r] += e4.x * f0 + e4.y * f1 + e4.z * f2 + e4.w * f3;
          aT2[r] += e4.x * p0 + e4.y * p1 + e4.z * p2 + e4.w * p3;
        }
      }
    }
#pragma unroll
    for (int r = 0; r < 13; ++r) {
      if (r < cnt13) {
        Ksh[(n0 + r) * RS + cc]   = aK[r];
        Vsh[(n0 + r) * RS + cc]   = aV[r];
        EQsh[(n0 + r) * RS + cc]  = aT1[r];
        KP2sh[(n0 + r) * RS + cc] = aT2[r];
      }
    }
  }
  __syncthreads();  // S3

  // ---- phase B (fused, in place): EQ = T1@wq ; KP2 = T2@wo^T ----
  {
    float aEQ[13], aKP[13];
#pragma unroll
    for (int r = 0; r < 13; ++r) { aEQ[r] = 0.f; aKP[r] = 0.f; }
    for (int i = 0; i < DD; i += 4) {
      const float q0 = wq[(i + 0) * DD + cc], q1 = wq[(i + 1) * DD + cc];
      const float q2 = wq[(i + 2) * DD + cc], q3 = wq[(i + 3) * DD + cc];
      const float4 w4 = *(const float4*)&wo[cc * DD + i];
#pragma unroll
      for (int r = 0; r < 13; ++r) {
        if (r < cnt13) {
          const float4 t1 = *(const float4*)&EQsh[(n0 + r) * RS + i];
          const float4 t2 = *(const float4*)&KP2sh[(n0 + r) * RS + i];
          aEQ[r] += t1.x * q0 + t1.y * q1 + t1.z * q2 + t1.w * q3;
          aKP[r] += dot4(t2, w4);
        }
      }
    }
    __syncthreads();  // S4
#pragma unroll
    for (int r = 0; r < 13; ++r) {
      if (r < cnt13) {
        EQsh[(n0 + r) * RS + cc]  = aEQ[r];
        KP2sh[(n0 + r) * RS + cc] = aKP[r];
      }
    }
  }
  __syncthreads();  // S5

  // ---- preload static per-(wave,lane) register slices ----
  const int rowc = (l < NN) ? l : 0;
  const float4* kbase = (const float4*)&Ksh[rowc * RS + w * 16];
  const float4 Kr0 = kbase[0], Kr1 = kbase[1], Kr2 = kbase[2], Kr3 = kbase[3];
  const float4* pbase = (const float4*)&KP2sh[rowc * RS + w * 16];
  const float4 Pr0 = pbase[0], Pr1 = pbase[1], Pr2 = pbase[2], Pr3 = pbase[3];
  // EQ row slice in registers: lane l holds EQ[l][w*16 + j]
  float EQr[16];
#pragma unroll
  for (int j = 0; j < 16; ++j) EQr[j] = EQsh[rowc * RS + w * 16 + j];
  const int nn0 = l & 15, dq = l >> 4;
  const int vr3 = (nn0 + 48 <= 51) ? (nn0 + 48) : 51;
  const float4 Vr0 = *(const float4*)&Vsh[(nn0 +  0) * RS + w * 16 + dq * 4];
  const float4 Vr1 = *(const float4*)&Vsh[(nn0 + 16) * RS + w * 16 + dq * 4];
  const float4 Vr2 = *(const float4*)&Vsh[(nn0 + 32) * RS + w * 16 + dq * 4];
  const float4 Vr3 = *(const float4*)&Vsh[vr3 * RS + w * 16 + dq * 4];
  const float4* wbase = (const float4*)&wrowL[w * 16];
  const float4 Wr0 = wbase[0], Wr1 = wbase[1], Wr2 = wbase[2], Wr3 = wbase[3];

  // ---- phase C: pool chain (1 barrier/t), then parallel @wq in place ----
  {
    const int colC = tid >> 2, qrt = tid & 3;
    float wfr[32];
#pragma unroll
    for (int i = 0; i < 32; ++i) wfr[i] = fc1[(qrt * 32 + i) * DD + colC];
    int cur = 0;
    for (int t = 0; t < ns; ++t) {
      float s = 0.f;
#pragma unroll
      for (int i = 0; i < 32; ++i) s += poolB[cur][qrt * 32 + i] * wfr[i];
      s = quad_sum(s);
      if (qrt == 0) {
        qpoolL[t * DD + colC] = s;      // pool_{t+1}
        poolB[cur ^ 1][colC] = s;
      }
      cur ^= 1;
      __syncthreads();
    }
    const int qch = (ns + 3) >> 2;
    const int r0 = g4 * qch;
    const int rcnt = (ns - r0 < qch) ? (ns - r0) : qch;
    float acc[16];
#pragma unroll
    for (int r = 0; r < 16; ++r) acc[r] = 0.f;
    for (int i = 0; i < DD; i += 4) {
      const float q0 = wq[(i + 0) * DD + cc], q1 = wq[(i + 1) * DD + cc];
      const float q2 = wq[(i + 2) * DD + cc], q3 = wq[(i + 3) * DD + cc];
#pragma unroll
      for (int r = 0; r < 16; ++r) {
        if (r < rcnt) {
          const float4 p4 = *(const float4*)&qpoolL[(r0 + r) * DD + i];
          acc[r] += p4.x * q0 + p4.y * q1 + p4.z * q2 + p4.w * q3;
        }
      }
    }
    __syncthreads();
#pragma unroll
    for (int r = 0; r < 16; ++r)
      if (r < rcnt) qpoolL[(r0 + r) * DD + cc] = acc[r];
  }
  __syncthreads();

  // ---- preloop: replicated register state + qv for t=0 ----
  int m1 = (l == 0) ? 1 : 0;
  float dynr = cap0, depotr = 1.f, lpacc0 = 0.f;
  float4 qv0, qv1, qv2, qv3;
  {
    const float4* eq = (const float4*)&EQsh[0 * RS + w * 16];
    const float4* qp = (const float4*)&qpoolL[0 * DD + w * 16];
    qv0.x = eq[0].x + cap0 * Wr0.x + qp[0].x; qv0.y = eq[0].y + cap0 * Wr0.y + qp[0].y;
    qv0.z = eq[0].z + cap0 * Wr0.z + qp[0].z; qv0.w = eq[0].w + cap0 * Wr0.w + qp[0].w;
    qv1.x = eq[1].x + cap0 * Wr1.x + qp[1].x; qv1.y = eq[1].y + cap0 * Wr1.y + qp[1].y;
    qv1.z = eq[1].z + cap0 * Wr1.z + qp[1].z; qv1.w = eq[1].w + cap0 * Wr1.w + qp[1].w;
    qv2.x = eq[2].x + cap0 * Wr2.x + qp[2].x; qv2.y = eq[2].y + cap0 * Wr2.y + qp[2].y;
    qv2.z = eq[2].z + cap0 * Wr2.z + qp[2].z; qv2.w = eq[2].w + cap0 * Wr2.w + qp[2].w;
    qv3.x = eq[3].x + cap0 * Wr3.x + qp[3].x; qv3.y = eq[3].y + cap0 * Wr3.y + qp[3].y;
    qv3.z = eq[3].z + cap0 * Wr3.z + qp[3].z; qv3.w = eq[3].w + cap0 * Wr3.w + qp[3].w;
  }

  // ---- decode: ONE barrier/step ----
  for (int t = 0; t < ns; ++t) {
    // X: head attention + comp partial (all waves)
    {
      const bool maskedl =
          (l == 0) ? (depotr > 0.f)
          : (l < NN ? ((m1 != 0) || (dem_l > dynr)) : true);
      float u1 = NINFF;
      if (l < NN && !maskedl)
        u1 = 0.25f * ((dot4(Kr0, qv0) + dot4(Kr1, qv1)) +
                      (dot4(Kr2, qv2) + dot4(Kr3, qv3)));
      const float mx = wave_max_b(u1);
      const float e = (u1 > NINFF) ? expf(u1 - mx) : 0.f;
      const float a0 = __shfl(e, nn0);
      const float a1 = __shfl(e, nn0 + 16);
      const float a2 = __shfl(e, nn0 + 32);
      const float a3 = __shfl(e, nn0 + 48);
      const float S = wave_sum_b(e);
      const float rS = 1.f / S;
      float ax = a0 * Vr0.x + a1 * Vr1.x + a2 * Vr2.x + a3 * Vr3.x;
      float ay = a0 * Vr0.y + a1 * Vr1.y + a2 * Vr2.y + a3 * Vr3.y;
      float az = a0 * Vr0.z + a1 * Vr1.z + a2 * Vr2.z + a3 * Vr3.z;
      float aw = a0 * Vr0.w + a1 * Vr1.w + a2 * Vr2.w + a3 * Vr3.w;
      ax = row16_sum(ax) * rS; ay = row16_sum(ay) * rS;
      az = row16_sum(az) * rS; aw = row16_sum(aw) * rS;
      const float g0  = readlanef(ax, 15), g1  = readlanef(ay, 15);
      const float g2  = readlanef(az, 15), g3  = readlanef(aw, 15);
      const float g4g = readlanef(ax, 31), g5  = readlanef(ay, 31);
      const float g6  = readlanef(az, 31), g7  = readlanef(aw, 31);
      const float g8  = readlanef(ax, 47), g9  = readlanef(ay, 47);
      const float g10 = readlanef(az, 47), g11 = readlanef(aw, 47);
      const float g12 = readlanef(ax, 63), g13 = readlanef(ay, 63);
      const float g14 = readlanef(az, 63), g15 = readlanef(aw, 63);
      const float part =
          ((Pr0.x * g0  + Pr0.y * g1  + Pr0.z * g2  + Pr0.w * g3) +
           (Pr1.x * g4g + Pr1.y * g5  + Pr1.z * g6  + Pr1.w * g7)) +
          ((Pr2.x * g8  + Pr2.y * g9  + Pr2.z * g10 + Pr2.w * g11) +
           (Pr3.x * g12 + Pr3.y * g13 + Pr3.z * g14 + Pr3.w * g15));
      pcb2[t & 1][w * 64 + l] = part;
    }
    __syncthreads();   // the ONLY barrier per step
    // Z: replicated sampling + state in every wave (symmetric)
    {
      // early best-independent prefetches
      const int qidx = (t + 1 < ns) ? (t + 1) : 0;
      const float4* qp = (const float4*)&qpoolL[qidx * DD + w * 16];
      const float4 qp0 = qp[0], qp1 = qp[1], qp2 = qp[2], qp3 = qp[3];
      const float pg = (!greedy && l < NN) ? gumT[t * NN + l] : 0.f;
      const float* pcb = pcb2[t & 1];
      float lgv = NINFF;
      {
        const float p0 = pcb[0 * 64 + l], p1 = pcb[1 * 64 + l];
        const float p2 = pcb[2 * 64 + l], p3 = pcb[3 * 64 + l];
        const float p4 = pcb[4 * 64 + l], p5 = pcb[5 * 64 + l];
        const float p6 = pcb[6 * 64 + l], p7 = pcb[7 * 64 + l];
        const float comp = (((p0 + p1) + (p2 + p3)) + ((p4 + p5) + (p6 + p7))) *
                           0.08838834764831845f;  // 128^-0.5
        const float lg = (10.f * tanhf(comp)) / Tval;
        const bool maskedn =
            (l == 0) ? (depotr > 0.f) : ((m1 != 0) || (dem_l > dynr));
        if (l < NN) lgv = maskedn ? NINFF : lg;
      }
      const float pv = (l < NN) ? (lgv + pg) : NINFF;
      const float vmax = wave_max_b(pv);
      const unsigned long long Meq = __ballot(pv == vmax);
      const int best = __ffsll(Meq) - 1;   // first max = jnp.argmax tie-break
      if (l == best) m1 = 1;
      const unsigned long long M = __ballot(m1 != 0);
      const int cntv = (int)__popcll(M & ~1ull);
      const float dem_b = readlanef(dem_l, best);
      dynr = (best == 0) ? cap0 : (dynr - dem_b);
      depotr = (best == 0) ? 1.f : 0.f;
      if (cntv >= NN - 1) depotr = 0.f;
      if (w == 0) {
        // stash logits into the DEAD qpool row t (row t fully consumed at Z(t-1))
        if (l < NN) qpoolL[t * DD + l] = lgv;
        lpacc0 += readlanef(lgv, best);
        if (l == 0) actsL[t] = (float)best;
      }
      // next q slice: EQ[best] via uniform readlane from register slice
      qv0.x = readlanef(EQr[ 0], best) + dynr * Wr0.x + qp0.x;
      qv0.y = readlanef(EQr[ 1], best) + dynr * Wr0.y + qp0.y;
      qv0.z = readlanef(EQr[ 2], best) + dynr * Wr0.z + qp0.z;
      qv0.w = readlanef(EQr[ 3], best) + dynr * Wr0.w + qp0.w;
      qv1.x = readlanef(EQr[ 4], best) + dynr * Wr1.x + qp1.x;
      qv1.y = readlanef(EQr[ 5], best) + dynr * Wr1.y + qp1.y;
      qv1.z = readlanef(EQr[ 6], best) + dynr * Wr1.z + qp1.z;
      qv1.w = readlanef(EQr[ 7], best) + dynr * Wr1.w + qp1.w;
      qv2.x = readlanef(EQr[ 8], best) + dynr * Wr2.x + qp2.x;
      qv2.y = readlanef(EQr[ 9], best) + dynr * Wr2.y + qp2.y;
      qv2.z = readlanef(EQr[10], best) + dynr * Wr2.z + qp2.z;
      qv2.w = readlanef(EQr[11], best) + dynr * Wr2.w + qp2.w;
      qv3.x = readlanef(EQr[12], best) + dynr * Wr3.x + qp3.x;
      qv3.y = readlanef(EQr[13], best) + dynr * Wr3.y + qp3.y;
      qv3.z = readlanef(EQr[14], best) + dynr * Wr3.z + qp3.z;
      qv3.w = readlanef(EQr[15], best) + dynr * Wr3.w + qp3.w;
    }
    // no barrier: pcb double-buffered; gumT read-only; qpool row t dead
  }
  __syncthreads();

  // ---- post-loop: LSE for all steps (8 waves x ~8 steps), then output ----
  {
    float lsum = 0.f;
    for (int t = w; t < ns; t += 8) {
      const float lv = (l < NN) ? qpoolL[t * DD + l] : NINFF;
      const float mm = wave_max_b(lv);
      const float ee = wave_sum_b((lv > NINFF) ? expf(lv - mm) : 0.f);
      lsum += mm + logf(ee);
    }
    if (l == 0) lseP[w] = lsum;
  }
  __syncthreads();
  if (w == 0 && l < ns) out[b * ns + l] = actsL[l];
  if (w == 0 && l == 0) {
    const float tot = ((lseP[0] + lseP[1]) + (lseP[2] + lseP[3])) +
                      ((lseP[4] + lseP[5]) + (lseP[6] + lseP[7]));
    out[Bn * ns + b] = lpacc0 - tot;
  }
}

extern "C" void kernel_launch(void* const* d_in, const int* in_sizes, int n_in,
                              void* d_out, int out_size, void* d_ws, size_t ws_size,
                              hipStream_t stream) {
  const float* enc    = (const float*)d_in[0];
  const float* pool   = (const float*)d_in[1];
  const float* cap    = (const float*)d_in[2];
  const float* dem    = (const float*)d_in[3];
  const float* fc_w   = (const float*)d_in[4];
  const float* fc1_w  = (const float*)d_in[5];
  const float* wq     = (const float*)d_in[6];
  const float* wk     = (const float*)d_in[7];
  const float* wv     = (const float*)d_in[8];
  const float* wo     = (const float*)d_in[9];
  const float* wkp    = (const float*)d_in[10];
  const float* Tp     = (const float*)d_in[11];
  const int*   nsp    = (const int*)d_in[12];
  const int*   greedy = (const int*)d_in[14];
  float* out = (float*)d_out;

  const int B = in_sizes[1] / DD;  // pool is (B,128)

  hipLaunchKernelGGL(decode_kernel, dim3(B), dim3(512), 0, stream,
                     enc, pool, cap, dem, fc_w, fc1_w, wq, wk, wv, wo, wkp,
                     Tp, nsp, greedy, out);
}